// Round 2
// baseline (170547.888 us; speedup 1.0000x reference)
//
#include <hip/hip_runtime.h>
#include <cstdint>
#include <cstddef>

// ---------------------------------------------------------------------------
// LSTM encoder: 5 layers, REVS = (T,F,T,F,T), B=64, T=1024, D=H=384, fp32.
// Per layer: xproj = x(rev)@Wi + b  (parallel GEMM), then sequential scan.
// Scan: persistent kernel, 192 wgs = 8 batch-groups x 24 col-chunks.
//   - Wh slice (384x64 fp32 = 98KB) persistent in LDS per wg.
//   - per-step cross-wg sync via agent-scope atomics (cross-XCD coherent).
//   - h exchange double-buffered in ws; counters monotonic (layer*1025+t).
// All layers stream in-place through d_out (region-disjointness by the
// shared bijective time map between gemm reads and recur writes).
// ---------------------------------------------------------------------------

#define T_SEQ   1024
#define DD      384
#define HH      384
#define FH      1536
#define NBATCH  64
#define BG      8      // batch per group
#define CC      24     // column chunks (64 cols each)
#define JHW     16     // h-columns per wg
#define RTHREADS 512
#define CNT_STRIDE 32  // ints -> 128B per counter line
#define SMEM_BYTES 129664
// LDS carve: WhL 384*64*4 = 98304 | hL 8*388*4 = 12416 | zred 8*64*9*4 = 18432 | cL 512

__device__ __forceinline__ float sigmoidf_(float x) {
  return 1.0f / (1.0f + __expf(-x));
}
__device__ __forceinline__ float tanhf_(float x) {
  float ax = fabsf(x);
  float e  = __expf(-2.0f * ax);
  float r  = (1.0f - e) / (1.0f + e);
  return (x >= 0.0f) ? r : -r;
}

// ---------------------------------------------------------------------------
// xproj GEMM: rows m = trel*64 + b  (M = Tc*64), cols j in [0,1536), K=384.
// A row = xin[b][tsrc][:], tsrc = rev ? 1023-(t0+trel) : t0+trel.
// 128x128 block, BK=8, 256 threads, 8x8 microtile.
// ---------------------------------------------------------------------------
__global__ __launch_bounds__(256) void gemm_xproj(
    const float* __restrict__ xin, const float* __restrict__ Wi,
    const float* __restrict__ bias, float* __restrict__ xproj,
    int t0, int rev)
{
  __shared__ float As[8][132];
  __shared__ float Bs[8][132];

  const int tid = threadIdx.x;
  const int tx = tid & 15, ty = tid >> 4;
  const int m0 = blockIdx.y * 128;
  const int j0 = blockIdx.x * 128;

  // A loader: one float4 per thread per k-tile
  const int r    = tid >> 1;
  const int part = tid & 1;
  const int m    = m0 + r;
  const int b    = m & 63;
  const int trel = m >> 6;
  const int t    = t0 + trel;
  const int tsrc = rev ? (T_SEQ - 1 - t) : t;
  const float* arow = xin + ((size_t)b * T_SEQ + tsrc) * DD + part * 4;

  // B loader
  const int kr = tid >> 5;
  const int jc = (tid & 31) << 2;
  const float* brow = Wi + (size_t)kr * FH + j0 + jc;

  float acc[8][8];
#pragma unroll
  for (int i = 0; i < 8; ++i)
#pragma unroll
    for (int j = 0; j < 8; ++j) acc[i][j] = 0.0f;

  for (int kt = 0; kt < 48; ++kt) {
    float4 av = *(const float4*)(arow + kt * 8);
    float4 bv = *(const float4*)(brow + (size_t)kt * 8 * FH);
    __syncthreads();
    As[part * 4 + 0][r] = av.x;
    As[part * 4 + 1][r] = av.y;
    As[part * 4 + 2][r] = av.z;
    As[part * 4 + 3][r] = av.w;
    *(float4*)&Bs[kr][jc] = bv;
    __syncthreads();
#pragma unroll
    for (int k = 0; k < 8; ++k) {
      float a[8], bb[8];
      *(float4*)&a[0]  = *(const float4*)&As[k][ty * 8];
      *(float4*)&a[4]  = *(const float4*)&As[k][ty * 8 + 4];
      *(float4*)&bb[0] = *(const float4*)&Bs[k][tx * 8];
      *(float4*)&bb[4] = *(const float4*)&Bs[k][tx * 8 + 4];
#pragma unroll
      for (int i = 0; i < 8; ++i)
#pragma unroll
        for (int j = 0; j < 8; ++j)
          acc[i][j] = fmaf(a[i], bb[j], acc[i][j]);
    }
  }

  float bvals[8];
#pragma unroll
  for (int j = 0; j < 8; ++j) bvals[j] = bias[j0 + tx * 8 + j];

#pragma unroll
  for (int i = 0; i < 8; ++i) {
    const int mm = m0 + ty * 8 + i;
    float* orow = xproj + (size_t)mm * FH + j0 + tx * 8;
    float4 o0, o1;
    o0.x = acc[i][0] + bvals[0]; o0.y = acc[i][1] + bvals[1];
    o0.z = acc[i][2] + bvals[2]; o0.w = acc[i][3] + bvals[3];
    o1.x = acc[i][4] + bvals[4]; o1.y = acc[i][5] + bvals[5];
    o1.z = acc[i][6] + bvals[6]; o1.w = acc[i][7] + bvals[7];
    *(float4*)(orow)     = o0;
    *(float4*)(orow + 4) = o1;
  }
}

// ---------------------------------------------------------------------------
// Persistent recurrence kernel. 192 blocks (<=256 CUs, 1 block/CU -> all
// co-resident), 512 threads = 8 waves. wg = bg*24 + cc.
// Columns of this wg: gate*384 + cc*16 + jj for gate in 0..3, jj in 0..15.
// ---------------------------------------------------------------------------
__global__ __launch_bounds__(RTHREADS) void lstm_recur(
    const float* __restrict__ xp, const float* __restrict__ Wh,
    float* __restrict__ xout, float* __restrict__ h_ex,
    float* __restrict__ c_state, int* __restrict__ counters,
    int t0, int Tc, int rev, int layer)
{
  extern __shared__ char smem[];
  float (*WhL)[64]  = (float (*)[64])(smem);
  float (*hL)[388]  = (float (*)[388])(smem + 98304);
  float* zred       = (float*)(smem + 110720);
  float* cL         = (float*)(smem + 129152);

  const int wg   = blockIdx.x;
  const int bg   = wg / CC;
  const int cc   = wg % CC;
  const int tid  = threadIdx.x;
  const int wave = tid >> 6;
  const int lane = tid & 63;
  const int base = layer * 1025;

  // --- load Wh slice into LDS (once per launch) ---
  for (int idx = tid; idx < 384 * 64; idx += RTHREADS) {
    int k = idx >> 6;
    int c = idx & 63;
    int col = ((c >> 4) * HH) + cc * JHW + (c & 15);
    WhL[k][c] = Wh[(size_t)k * FH + col];
  }

  const int rb    = tid >> 4;          // valid for tid<128
  const int rjj   = tid & 15;
  const int bglob = bg * BG + rb;
  const int hb    = cc * JHW + rjj;

  if (tid < 128) {
    cL[tid] = (t0 == 0) ? 0.0f : c_state[(size_t)bglob * HH + hb];
  }
  if (t0 == 0 && tid < 128) {
    // zero-publish h_{-1} into parity-1 buffer
    h_ex[(size_t)(NBATCH * HH) + (size_t)bglob * HH + hb] = 0.0f;
  }
  __syncthreads();   // drains vmem -> zero stores visible
  if (t0 == 0 && tid == 0) {
    __threadfence();   // agent-scope release
    __hip_atomic_store(&counters[wg * CNT_STRIDE], base + 1,
                       __ATOMIC_RELAXED, __HIP_MEMORY_SCOPE_AGENT);
  }

  const int k0 = wave * 48;

  for (int tr = 0; tr < Tc; ++tr) {
    const int t = t0 + tr;

    // prefetch xproj gate values (independent of peers -> hide under spin)
    float xpr0 = 0.f, xpr1 = 0.f, xpr2 = 0.f, xpr3 = 0.f;
    if (tid < 128) {
      const float* xr = xp + ((size_t)tr * NBATCH + bglob) * FH + cc * JHW + rjj;
      xpr0 = xr[0];
      xpr1 = xr[384];
      xpr2 = xr[768];
      xpr3 = xr[1152];
    }

    // spin: wait until every wg of this batch-group published h_{t-1}
    if (wave == 0 && lane < CC) {
      const int target = base + t + 1;
      while (__hip_atomic_load(&counters[(bg * CC + lane) * CNT_STRIDE],
                               __ATOMIC_RELAXED,
                               __HIP_MEMORY_SCOPE_AGENT) < target) {
      }
    }
    __syncthreads();
    __threadfence();   // agent-scope acquire

    // stage h_{t-1} (this batch-group's 8x384) into LDS
    {
      const float* hsrc = h_ex + (size_t)((t + 1) & 1) * (NBATCH * HH)
                               + (size_t)bg * BG * HH;
      for (int f = tid; f < 768; f += RTHREADS) {
        int bb = f / 96;
        int kq = f - bb * 96;
        float4 v = *(const float4*)(hsrc + bb * HH + kq * 4);
        *(float4*)&hL[bb][kq * 4] = v;
      }
    }
    __syncthreads();

    // K-split partials: wave handles k in [wave*48, wave*48+48)
    float acc[8] = {0, 0, 0, 0, 0, 0, 0, 0};
#pragma unroll 4
    for (int q = 0; q < 12; ++q) {
      const int k = k0 + q * 4;
      const float w0 = WhL[k][lane];
      const float w1 = WhL[k + 1][lane];
      const float w2 = WhL[k + 2][lane];
      const float w3 = WhL[k + 3][lane];
#pragma unroll
      for (int bb = 0; bb < 8; ++bb) {
        float4 h4 = *(const float4*)&hL[bb][k];
        acc[bb] = fmaf(w0, h4.x, acc[bb]);
        acc[bb] = fmaf(w1, h4.y, acc[bb]);
        acc[bb] = fmaf(w2, h4.z, acc[bb]);
        acc[bb] = fmaf(w3, h4.w, acc[bb]);
      }
    }
#pragma unroll
    for (int bb = 0; bb < 8; ++bb)
      zred[(bb * 64 + lane) * 9 + wave] = acc[bb];
    __syncthreads();

    // reduce partials, gate math, publish h
    if (tid < 128) {
      float zi = xpr0, zf = xpr1, zg = xpr2, zo = xpr3;
#pragma unroll
      for (int w = 0; w < 8; ++w) {
        zi += zred[(rb * 64 +  0 + rjj) * 9 + w];
        zf += zred[(rb * 64 + 16 + rjj) * 9 + w];
        zg += zred[(rb * 64 + 32 + rjj) * 9 + w];
        zo += zred[(rb * 64 + 48 + rjj) * 9 + w];
      }
      float c = cL[tid];
      c = sigmoidf_(zf) * c + sigmoidf_(zi) * tanhf_(zg);
      float h = sigmoidf_(zo) * tanhf_(c);
      cL[tid] = c;
      h_ex[(size_t)(t & 1) * (NBATCH * HH) + (size_t)bglob * HH + hb] = h;
      const int to = rev ? (T_SEQ - 1 - t) : t;
      xout[((size_t)bglob * T_SEQ + to) * HH + hb] = h;
    }
    __syncthreads();   // h stores issued by all lanes
    if (tid == 0) {
      __threadfence();   // agent-scope release
      __hip_atomic_store(&counters[wg * CNT_STRIDE], base + t + 2,
                         __ATOMIC_RELAXED, __HIP_MEMORY_SCOPE_AGENT);
    }
  }

  // save c for the next chunk launch
  if (tid < 128) {
    c_state[(size_t)bglob * HH + hb] = cL[tid];
  }
}

// ---------------------------------------------------------------------------
extern "C" void kernel_launch(void* const* d_in, const int* in_sizes, int n_in,
                              void* d_out, int out_size, void* d_ws, size_t ws_size,
                              hipStream_t stream) {
  (void)in_sizes; (void)n_in; (void)out_size;

  const float* x  = (const float*)d_in[0];
  const float* Wi = (const float*)d_in[1];
  const float* Wh = (const float*)d_in[2];
  const float* bs = (const float*)d_in[3];
  float* out = (float*)d_out;

  char*  ws       = (char*)d_ws;
  int*   counters = (int*)ws;                               // 24576 B
  float* c_state  = (float*)(ws + 24576);                   // 98304 B
  float* h_ex     = (float*)(ws + 24576 + 98304);           // 196608 B
  float* xproj    = (float*)(ws + 24576 + 98304 + 196608);
  const size_t fixed = 24576 + 98304 + 196608;

  // adaptive time-chunk so xproj fits in ws
  int Tc = 1024;
  while (Tc > 8 && fixed + (size_t)Tc * NBATCH * FH * 4 > ws_size) Tc >>= 1;

  (void)hipFuncSetAttribute((const void*)lstm_recur,
                            hipFuncAttributeMaxDynamicSharedMemorySize,
                            SMEM_BYTES);
  (void)hipMemsetAsync(counters, 0, 24576, stream);

  const int revs[5] = {1, 0, 1, 0, 1};
  for (int l = 0; l < 5; ++l) {
    const float* xin = (l == 0) ? x : out;
    for (int t0 = 0; t0 < T_SEQ; t0 += Tc) {
      dim3 g(FH / 128, (unsigned)((Tc * NBATCH) / 128));
      gemm_xproj<<<g, 256, 0, stream>>>(xin, Wi + (size_t)l * DD * FH,
                                        bs + (size_t)l * FH, xproj, t0, revs[l]);
      lstm_recur<<<192, RTHREADS, SMEM_BYTES, stream>>>(
          xproj, Wh + (size_t)l * DD * FH, out, h_ex, c_state, counters,
          t0, Tc, revs[l], l);
    }
  }
}

// Round 3
// 30835.620 us; speedup vs baseline: 5.5309x; 5.5309x over previous
//
#include <hip/hip_runtime.h>
#include <cstdint>
#include <cstddef>

// ---------------------------------------------------------------------------
// LSTM encoder: 5 layers, REVS = (T,F,T,F,T), B=64, T=1024, D=H=384, fp32.
// Per layer: xproj = x(rev)@Wi + b  (parallel GEMM), then sequential scan.
// Scan: persistent kernel, 192 wgs = 8 batch-groups x 24 col-chunks.
//   - Wh slice (384x64 fp32 = 98KB) persistent in LDS per wg.
//   - h exchange via SELF-VALIDATING 64-bit agent-scope relaxed atomics:
//     each element packs (tag<<32)|float_bits, tag = layer*1025 + t + 1.
//     No fences -> no per-step L2 writeback/invalidate (the R2 killer).
//   - double-buffered h slots by t&1; tags unique across layers/chunks.
// ---------------------------------------------------------------------------

#define T_SEQ   1024
#define DD      384
#define HH      384
#define FH      1536
#define NBATCH  64
#define BG      8      // batch rows per group
#define CC      24     // column chunks (64 gate-cols each -> 16 h-cols)
#define JHW     16     // h-columns per wg
#define RTHREADS 512
#define SMEM_BYTES 129664
// LDS carve: WhL 384*64*4 = 98304 | hL 8*388*4 = 12416 | zred 8*64*9*4 = 18432 | cL 512

typedef unsigned long long u64;

__device__ __forceinline__ float sigmoidf_(float x) {
  return 1.0f / (1.0f + __expf(-x));
}
__device__ __forceinline__ float tanhf_(float x) {
  float ax = fabsf(x);
  float e  = __expf(-2.0f * ax);
  float r  = (1.0f - e) / (1.0f + e);
  return (x >= 0.0f) ? r : -r;
}

// ---------------------------------------------------------------------------
// xproj GEMM: rows m = trel*64 + b  (M = Tc*64), cols j in [0,1536), K=384.
// 128x128 block, BK=8, 256 threads, 8x8 microtile.
// ---------------------------------------------------------------------------
__global__ __launch_bounds__(256) void gemm_xproj(
    const float* __restrict__ xin, const float* __restrict__ Wi,
    const float* __restrict__ bias, float* __restrict__ xproj,
    int t0, int rev)
{
  __shared__ float As[8][132];
  __shared__ float Bs[8][132];

  const int tid = threadIdx.x;
  const int tx = tid & 15, ty = tid >> 4;
  const int m0 = blockIdx.y * 128;
  const int j0 = blockIdx.x * 128;

  const int r    = tid >> 1;
  const int part = tid & 1;
  const int m    = m0 + r;
  const int b    = m & 63;
  const int trel = m >> 6;
  const int t    = t0 + trel;
  const int tsrc = rev ? (T_SEQ - 1 - t) : t;
  const float* arow = xin + ((size_t)b * T_SEQ + tsrc) * DD + part * 4;

  const int kr = tid >> 5;
  const int jc = (tid & 31) << 2;
  const float* brow = Wi + (size_t)kr * FH + j0 + jc;

  float acc[8][8];
#pragma unroll
  for (int i = 0; i < 8; ++i)
#pragma unroll
    for (int j = 0; j < 8; ++j) acc[i][j] = 0.0f;

  for (int kt = 0; kt < 48; ++kt) {
    float4 av = *(const float4*)(arow + kt * 8);
    float4 bv = *(const float4*)(brow + (size_t)kt * 8 * FH);
    __syncthreads();
    As[part * 4 + 0][r] = av.x;
    As[part * 4 + 1][r] = av.y;
    As[part * 4 + 2][r] = av.z;
    As[part * 4 + 3][r] = av.w;
    *(float4*)&Bs[kr][jc] = bv;
    __syncthreads();
#pragma unroll
    for (int k = 0; k < 8; ++k) {
      float a[8], bb[8];
      *(float4*)&a[0]  = *(const float4*)&As[k][ty * 8];
      *(float4*)&a[4]  = *(const float4*)&As[k][ty * 8 + 4];
      *(float4*)&bb[0] = *(const float4*)&Bs[k][tx * 8];
      *(float4*)&bb[4] = *(const float4*)&Bs[k][tx * 8 + 4];
#pragma unroll
      for (int i = 0; i < 8; ++i)
#pragma unroll
        for (int j = 0; j < 8; ++j)
          acc[i][j] = fmaf(a[i], bb[j], acc[i][j]);
    }
  }

  float bvals[8];
#pragma unroll
  for (int j = 0; j < 8; ++j) bvals[j] = bias[j0 + tx * 8 + j];

#pragma unroll
  for (int i = 0; i < 8; ++i) {
    const int mm = m0 + ty * 8 + i;
    float* orow = xproj + (size_t)mm * FH + j0 + tx * 8;
    float4 o0, o1;
    o0.x = acc[i][0] + bvals[0]; o0.y = acc[i][1] + bvals[1];
    o0.z = acc[i][2] + bvals[2]; o0.w = acc[i][3] + bvals[3];
    o1.x = acc[i][4] + bvals[4]; o1.y = acc[i][5] + bvals[5];
    o1.z = acc[i][6] + bvals[6]; o1.w = acc[i][7] + bvals[7];
    *(float4*)(orow)     = o0;
    *(float4*)(orow + 4) = o1;
  }
}

// ---------------------------------------------------------------------------
// Persistent recurrence kernel. 192 blocks x 512 threads (8 waves), 1/CU.
// wg = bg*24 + cc. Gate columns: gate*384 + cc*16 + jj.
// ---------------------------------------------------------------------------
__global__ __launch_bounds__(RTHREADS) void lstm_recur(
    const float* __restrict__ xp, const float* __restrict__ Wh,
    float* __restrict__ xout, u64* __restrict__ h_ex,
    float* __restrict__ c_state,
    int t0, int Tc, int rev, int layer)
{
  extern __shared__ char smem[];
  float (*WhL)[64]  = (float (*)[64])(smem);
  float (*hL)[388]  = (float (*)[388])(smem + 98304);
  float* zred       = (float*)(smem + 110720);
  float* cL         = (float*)(smem + 129152);

  const int wg   = blockIdx.x;
  const int bg   = wg / CC;
  const int cc   = wg % CC;
  const int tid  = threadIdx.x;
  const int wave = tid >> 6;
  const int lane = tid & 63;
  const unsigned base = (unsigned)(layer * 1025);  // tag(h_t) = base + t + 1

  // --- load Wh slice into LDS (once per launch) ---
  for (int idx = tid; idx < 384 * 64; idx += RTHREADS) {
    int k = idx >> 6;
    int c = idx & 63;
    int col = ((c >> 4) * HH) + cc * JHW + (c & 15);
    WhL[k][c] = Wh[(size_t)k * FH + col];
  }

  const int rb    = tid >> 4;          // valid for tid<128
  const int rjj   = tid & 15;
  const int bglob = bg * BG + rb;
  const int hb    = cc * JHW + rjj;

  if (tid < 128) {
    cL[tid] = (t0 == 0) ? 0.0f : c_state[(size_t)bglob * HH + hb];
    if (t0 == 0) {
      // publish h_{-1}=0 into slot 1 with tag=base (self-validating)
      u64 pack = ((u64)base << 32);
      __hip_atomic_store(&h_ex[(size_t)(NBATCH * HH) + (size_t)bglob * HH + hb],
                         pack, __ATOMIC_RELAXED, __HIP_MEMORY_SCOPE_AGENT);
    }
  }
  __syncthreads();

  const int k0 = wave * 48;

  for (int tr = 0; tr < Tc; ++tr) {
    const int t = t0 + tr;

    // prefetch xproj gate values (independent of peers -> hides under spin)
    float xpr0 = 0.f, xpr1 = 0.f, xpr2 = 0.f, xpr3 = 0.f;
    if (tid < 128) {
      const float* xr = xp + ((size_t)tr * NBATCH + bglob) * FH + cc * JHW + rjj;
      xpr0 = xr[0];
      xpr1 = xr[384];
      xpr2 = xr[768];
      xpr3 = xr[1152];
    }

    // stage h_{t-1} (this bg's 8x384) from tagged u64 exchange into LDS
    {
      const unsigned tagT = base + (unsigned)t;   // tag of h_{t-1}
      const u64* hsrc = h_ex + (size_t)((t + 1) & 1) * (NBATCH * HH)
                             + (size_t)bg * BG * HH;
      u64 v[6];
#pragma unroll
      for (int k = 0; k < 6; ++k)
        v[k] = __hip_atomic_load(&hsrc[tid + k * RTHREADS],
                                 __ATOMIC_RELAXED, __HIP_MEMORY_SCOPE_AGENT);
#pragma unroll
      for (int k = 0; k < 6; ++k) {
        while ((unsigned)(v[k] >> 32) != tagT) {
          v[k] = __hip_atomic_load(&hsrc[tid + k * RTHREADS],
                                   __ATOMIC_RELAXED, __HIP_MEMORY_SCOPE_AGENT);
        }
        const int e  = tid + k * RTHREADS;
        const int bb = e / HH;
        const int cl = e - bb * HH;
        hL[bb][cl] = __uint_as_float((unsigned)v[k]);
      }
    }
    __syncthreads();

    // K-split partials: wave handles k in [wave*48, wave*48+48)
    float acc[8] = {0, 0, 0, 0, 0, 0, 0, 0};
#pragma unroll 4
    for (int q = 0; q < 12; ++q) {
      const int k = k0 + q * 4;
      const float w0 = WhL[k][lane];
      const float w1 = WhL[k + 1][lane];
      const float w2 = WhL[k + 2][lane];
      const float w3 = WhL[k + 3][lane];
#pragma unroll
      for (int bb = 0; bb < 8; ++bb) {
        float4 h4 = *(const float4*)&hL[bb][k];
        acc[bb] = fmaf(w0, h4.x, acc[bb]);
        acc[bb] = fmaf(w1, h4.y, acc[bb]);
        acc[bb] = fmaf(w2, h4.z, acc[bb]);
        acc[bb] = fmaf(w3, h4.w, acc[bb]);
      }
    }
#pragma unroll
    for (int bb = 0; bb < 8; ++bb)
      zred[(bb * 64 + lane) * 9 + wave] = acc[bb];
    __syncthreads();

    // reduce partials, gate math, publish h (tagged atomic, no fence)
    if (tid < 128) {
      float zi = xpr0, zf = xpr1, zg = xpr2, zo = xpr3;
#pragma unroll
      for (int w = 0; w < 8; ++w) {
        zi += zred[(rb * 64 +  0 + rjj) * 9 + w];
        zf += zred[(rb * 64 + 16 + rjj) * 9 + w];
        zg += zred[(rb * 64 + 32 + rjj) * 9 + w];
        zo += zred[(rb * 64 + 48 + rjj) * 9 + w];
      }
      float c = cL[tid];
      c = sigmoidf_(zf) * c + sigmoidf_(zi) * tanhf_(zg);
      float h = sigmoidf_(zo) * tanhf_(c);
      cL[tid] = c;
      u64 pack = ((u64)(base + (unsigned)t + 1u) << 32)
               | (u64)__float_as_uint(h);
      __hip_atomic_store(&h_ex[(size_t)(t & 1) * (NBATCH * HH)
                               + (size_t)bglob * HH + hb],
                         pack, __ATOMIC_RELAXED, __HIP_MEMORY_SCOPE_AGENT);
      const int to = rev ? (T_SEQ - 1 - t) : t;
      xout[((size_t)bglob * T_SEQ + to) * HH + hb] = h;
    }
    __syncthreads();
  }

  // save c for the next chunk launch
  if (tid < 128) {
    c_state[(size_t)bglob * HH + hb] = cL[tid];
  }
}

// ---------------------------------------------------------------------------
extern "C" void kernel_launch(void* const* d_in, const int* in_sizes, int n_in,
                              void* d_out, int out_size, void* d_ws, size_t ws_size,
                              hipStream_t stream) {
  (void)in_sizes; (void)n_in; (void)out_size;

  const float* x  = (const float*)d_in[0];
  const float* Wi = (const float*)d_in[1];
  const float* Wh = (const float*)d_in[2];
  const float* bs = (const float*)d_in[3];
  float* out = (float*)d_out;

  char*  ws      = (char*)d_ws;
  float* c_state = (float*)ws;                       // 98304 B
  u64*   h_ex    = (u64*)(ws + 98304);               // 2*64*384*8 = 393216 B
  float* xproj   = (float*)(ws + 98304 + 393216);
  const size_t fixed = 98304 + 393216;

  // adaptive time-chunk so xproj fits in ws
  int Tc = 1024;
  while (Tc > 8 && fixed + (size_t)Tc * NBATCH * FH * 4 > ws_size) Tc >>= 1;

  (void)hipFuncSetAttribute((const void*)lstm_recur,
                            hipFuncAttributeMaxDynamicSharedMemorySize,
                            SMEM_BYTES);

  const int revs[5] = {1, 0, 1, 0, 1};
  for (int l = 0; l < 5; ++l) {
    const float* xin = (l == 0) ? x : out;
    for (int t0 = 0; t0 < T_SEQ; t0 += Tc) {
      dim3 g(FH / 128, (unsigned)((Tc * NBATCH) / 128));
      gemm_xproj<<<g, 256, 0, stream>>>(xin, Wi + (size_t)l * DD * FH,
                                        bs + (size_t)l * FH, xproj, t0, revs[l]);
      lstm_recur<<<192, RTHREADS, SMEM_BYTES, stream>>>(
          xproj, Wh + (size_t)l * DD * FH, out, h_ex, c_state,
          t0, Tc, revs[l], l);
    }
  }
}